// Round 8
// baseline (409.197 us; speedup 1.0000x reference)
//
#include <hip/hip_runtime.h>
#include <hip/hip_bf16.h>
#include <cstdint>

#define NEG_SLOPE 0.2f
#define SCAN_ELEMS 1024   // elements per scan block (256 thr x 4)
#define BUCKET_SHIFT 9    // 512 nodes per bucket
#define CHUNK 8192        // edges per bucketing block

__device__ inline unsigned short f2bf(float f) {  // round-to-nearest-even
    unsigned xi = __float_as_uint(f);
    unsigned r = xi + 0x7fffu + ((xi >> 16) & 1u);
    return (unsigned short)(r >> 16);
}
__device__ inline float bflo(unsigned g) { return __uint_as_float((g & 0xffffu) << 16); }
__device__ inline float bfhi(unsigned g) { return __uint_as_float(g & 0xffff0000u); }

// ---------------------------------------------------------------------------
// int64-vs-int32 edge_index detection (odd words of src row all zero => i64).
// ---------------------------------------------------------------------------
__global__ __launch_bounds__(256) void detect_kernel(const int* __restrict__ ei,
                                                     int* __restrict__ flag) {
    __shared__ int red[256];
    int t = threadIdx.x;
    int v = 0;
    for (int i = t; i < 2048; i += 256) v |= ei[2 * i + 1];
    red[t] = v;
    __syncthreads();
    for (int off = 128; off; off >>= 1) {
        if (t < off) red[t] |= red[t + off];
        __syncthreads();
    }
    if (t == 0) *flag = (red[0] == 0) ? 1 : 0;
}

__device__ inline int get_ei(const int* ei, int is64, long idx) {
    return is64 ? ei[2 * idx] : ei[(int)idx];
}

// ---------------------------------------------------------------------------
// Counting-sort CSR build.
// ---------------------------------------------------------------------------
__global__ __launch_bounds__(256) void p1_hist(const int* __restrict__ ei,
                                               const int* __restrict__ flag,
                                               int* __restrict__ HH,
                                               int E, int n, int nblk) {
    __shared__ int cnt[256];
    int tid = threadIdx.x;
    int nbuk = (n + (1 << BUCKET_SHIFT) - 1) >> BUCKET_SHIFT;  // <=256
    for (int b = tid; b < nbuk; b += 256) cnt[b] = 0;
    __syncthreads();
    int is64 = *flag;
    int total = E + n;
    int beg = blockIdx.x * CHUNK;
    int end = beg + CHUNK; if (end > total) end = total;
    for (int i = beg + tid; i < end; i += 256) {
        int d = (i < E) ? get_ei(ei, is64, (long)E + i) : (i - E);
        atomicAdd(&cnt[d >> BUCKET_SHIFT], 1);
    }
    __syncthreads();
    for (int b = tid; b < nbuk; b += 256) HH[b * nblk + blockIdx.x] = cnt[b];
}

__global__ __launch_bounds__(256) void scan1_kernel(const int* __restrict__ src,
                                                    int* __restrict__ bsums, int n) {
    int t = threadIdx.x;
    int i0 = blockIdx.x * SCAN_ELEMS + 4 * t;
    int4 v = make_int4(0, 0, 0, 0);
    if (i0 + 3 < n) v = *(const int4*)(src + i0);
    else {
        if (i0 + 0 < n) v.x = src[i0 + 0];
        if (i0 + 1 < n) v.y = src[i0 + 1];
        if (i0 + 2 < n) v.z = src[i0 + 2];
        if (i0 + 3 < n) v.w = src[i0 + 3];
    }
    int s = v.x + v.y + v.z + v.w;
#pragma unroll
    for (int off = 32; off; off >>= 1) s += __shfl_down(s, off);
    __shared__ int ws[4];
    if ((t & 63) == 0) ws[t >> 6] = s;
    __syncthreads();
    if (t == 0) bsums[blockIdx.x] = ws[0] + ws[1] + ws[2] + ws[3];
}

__global__ __launch_bounds__(256) void scan2_kernel(int* __restrict__ bsums, int nb) {
    __shared__ int sh[256];
    int t = threadIdx.x;
    int v = (t < nb) ? bsums[t] : 0;
    sh[t] = v;
    __syncthreads();
    for (int off = 1; off < 256; off <<= 1) {
        int u = (t >= off) ? sh[t - off] : 0;
        __syncthreads();
        sh[t] += u;
        __syncthreads();
    }
    if (t < nb) bsums[t] = sh[t] - v;
}

__global__ __launch_bounds__(256) void scan3g_kernel(const int* __restrict__ src,
                                                     const int* __restrict__ bsums,
                                                     int* __restrict__ out, int n) {
    int b = blockIdx.x;
    int t = threadIdx.x;
    int i0 = b * SCAN_ELEMS + 4 * t;
    int4 v = make_int4(0, 0, 0, 0);
    if (i0 + 3 < n) v = *(const int4*)(src + i0);
    else {
        if (i0 + 0 < n) v.x = src[i0 + 0];
        if (i0 + 1 < n) v.y = src[i0 + 1];
        if (i0 + 2 < n) v.z = src[i0 + 2];
        if (i0 + 3 < n) v.w = src[i0 + 3];
    }
    int s0 = v.x, s1 = s0 + v.y, s2 = s1 + v.z, s3 = s2 + v.w;
    __shared__ int sh[256];
    sh[t] = s3;
    __syncthreads();
    for (int off = 1; off < 256; off <<= 1) {
        int u = (t >= off) ? sh[t - off] : 0;
        __syncthreads();
        sh[t] += u;
        __syncthreads();
    }
    int base = bsums[b] + sh[t] - s3;
    if (i0 + 0 < n) out[i0 + 0] = base;
    if (i0 + 1 < n) out[i0 + 1] = base + s0;
    if (i0 + 2 < n) out[i0 + 2] = base + s1;
    if (i0 + 3 < n) out[i0 + 3] = base + s2;
}

// p3: scatter edges into bucket-sorted PACKED array (s<<9 | d&511).
__global__ __launch_bounds__(256) void p3_scatter(const int* __restrict__ ei,
                                                  const int* __restrict__ flag,
                                                  const int* __restrict__ scanHH,
                                                  int* __restrict__ sorted,
                                                  int E, int n, int nblk) {
    __shared__ int base[256];
    __shared__ int cur[256];
    int tid = threadIdx.x;
    int nbuk = (n + (1 << BUCKET_SHIFT) - 1) >> BUCKET_SHIFT;
    for (int b = tid; b < nbuk; b += 256) {
        base[b] = scanHH[b * nblk + blockIdx.x];
        cur[b] = 0;
    }
    __syncthreads();
    int is64 = *flag;
    int total = E + n;
    int beg = blockIdx.x * CHUNK;
    int end = beg + CHUNK; if (end > total) end = total;
    for (int i = beg + tid; i < end; i += 256) {
        int s, d;
        if (i < E) {
            s = get_ei(ei, is64, i);
            d = get_ei(ei, is64, (long)E + i);
        } else {
            s = d = i - E;
        }
        int b = d >> BUCKET_SHIFT;
        int p = base[b] + atomicAdd(&cur[b], 1);
        sorted[p] = (s << BUCKET_SHIFT) | (d & ((1 << BUCKET_SHIFT) - 1));
    }
}

// p4: one block per bucket -> ptr + csr_src.
__global__ __launch_bounds__(256) void p4_finalize(const int* __restrict__ scanHH,
                                                   const int* __restrict__ sorted,
                                                   int* __restrict__ ptr,
                                                   int* __restrict__ csr_src,
                                                   int n, int nblk, int T) {
    int b = blockIdx.x;
    int nbuk = gridDim.x;
    int tid = threadIdx.x;
    int node0 = b << BUCKET_SHIFT;
    int nn = n - node0; if (nn > (1 << BUCKET_SHIFT)) nn = 1 << BUCKET_SHIFT;
    int beg = scanHH[b * nblk];
    int end = (b + 1 < nbuk) ? scanHH[(b + 1) * nblk] : T;

    __shared__ int cnt[512];
    __shared__ int pair[256];
    __shared__ int exc[512];
    cnt[tid] = 0; cnt[tid + 256] = 0;
    __syncthreads();
    for (int j = beg + tid; j < end; j += 256) {
        int v = sorted[j];
        atomicAdd(&cnt[v & ((1 << BUCKET_SHIFT) - 1)], 1);
    }
    __syncthreads();
    int psum = cnt[2 * tid] + cnt[2 * tid + 1];
    pair[tid] = psum;
    __syncthreads();
    for (int off = 1; off < 256; off <<= 1) {
        int u = (tid >= off) ? pair[tid - off] : 0;
        __syncthreads();
        pair[tid] += u;
        __syncthreads();
    }
    int pexc = pair[tid] - psum;
    exc[2 * tid] = pexc;
    exc[2 * tid + 1] = pexc + cnt[2 * tid];
    __syncthreads();
    for (int i = tid; i < nn; i += 256) ptr[node0 + i] = beg + exc[i];
    if (node0 + nn == n && tid == 0) ptr[n] = T;
    cnt[tid] = exc[tid]; cnt[tid + 256] = exc[tid + 256];
    __syncthreads();
    for (int j = beg + tid; j < end; j += 256) {
        int v = sorted[j];
        int p = beg + atomicAdd(&cnt[v & ((1 << BUCKET_SHIFT) - 1)], 1);
        csr_src[p] = ((unsigned)v) >> BUCKET_SHIFT;
    }
}

// ---------------------------------------------------------------------------
// Projection as register-tiled GEMM; emits bf16 h2 + fp32 asrc/adst.
// ---------------------------------------------------------------------------
template <int K>
__global__ __launch_bounds__(256) void proj_gemm(const float* __restrict__ x,
                                                 const float* __restrict__ W,
                                                 const float* __restrict__ att_s,
                                                 const float* __restrict__ att_d,
                                                 unsigned short* __restrict__ h2,
                                                 float* __restrict__ asrc,
                                                 float* __restrict__ adst, int n) {
    constexpr int KP = K + 4;
    constexpr int ROWF4 = K / 4;
    __shared__ float xs[64 * KP];
    int tid = threadIdx.x;
    int node0 = blockIdx.x * 64;

#pragma unroll
    for (int r = 0; r < (64 * ROWF4) / 256; ++r) {
        int f4 = tid + 256 * r;
        int row = f4 / ROWF4, c4 = f4 % ROWF4;
        float4 v = make_float4(0.f, 0.f, 0.f, 0.f);
        if (node0 + row < n) v = *(const float4*)(x + (size_t)(node0 + row) * K + 4 * c4);
        *(float4*)(xs + row * KP + 4 * c4) = v;
    }
    __syncthreads();

    int tf = tid & 15, tn = tid >> 4;
    float acc[4][4];
#pragma unroll
    for (int i = 0; i < 4; ++i)
#pragma unroll
        for (int j = 0; j < 4; ++j) acc[i][j] = 0.f;

    const float* wp = W + 4 * tf;
    const float* xp = xs + 4 * tn * KP;
#pragma unroll 4
    for (int k4 = 0; k4 < K / 4; ++k4) {
        float4 wv[4];
#pragma unroll
        for (int kk = 0; kk < 4; ++kk)
            wv[kk] = *(const float4*)(wp + (size_t)(4 * k4 + kk) * 64);
        float4 xv[4];
#pragma unroll
        for (int i = 0; i < 4; ++i)
            xv[i] = *(const float4*)(xp + i * KP + 4 * k4);
#pragma unroll
        for (int i = 0; i < 4; ++i) {
            const float xk[4] = {xv[i].x, xv[i].y, xv[i].z, xv[i].w};
#pragma unroll
            for (int kk = 0; kk < 4; ++kk) {
                const float* wf = (const float*)&wv[kk];
#pragma unroll
                for (int j = 0; j < 4; ++j) acc[i][j] = fmaf(xk[kk], wf[j], acc[i][j]);
            }
        }
    }

    float4 as = *(const float4*)(att_s + 4 * tf);
    float4 ad = *(const float4*)(att_d + 4 * tf);
#pragma unroll
    for (int i = 0; i < 4; ++i) {
        int node = node0 + 4 * tn + i;
        float ps = acc[i][0] * as.x + acc[i][1] * as.y + acc[i][2] * as.z + acc[i][3] * as.w;
        float pd = acc[i][0] * ad.x + acc[i][1] * ad.y + acc[i][2] * ad.z + acc[i][3] * ad.w;
#pragma unroll
        for (int off = 1; off < 16; off <<= 1) {
            ps += __shfl_xor(ps, off);
            pd += __shfl_xor(pd, off);
        }
        if (node < n) {
            ushort4 u;
            u.x = f2bf(acc[i][0]); u.y = f2bf(acc[i][1]);
            u.z = f2bf(acc[i][2]); u.w = f2bf(acc[i][3]);
            *(ushort4*)(h2 + (size_t)node * 64 + 4 * tf) = u;
            if (tf == 0) { asrc[node] = ps; adst[node] = pd; }
        }
    }
}

// ---------------------------------------------------------------------------
// Fused edge softmax + aggregation, half-wave ushort2 scheme, unroll x8.
// One wave per node. FMEAN: per-block partial mean rows (no atomics here).
// ---------------------------------------------------------------------------
template <bool FMEAN>
__global__ __launch_bounds__(256) void agg_kernel(const int* __restrict__ ptr,
                                                  const int* __restrict__ srcs,
                                                  const unsigned short* __restrict__ h2,
                                                  const float* __restrict__ asrc,
                                                  const float* __restrict__ adst,
                                                  const float* __restrict__ bias,
                                                  float* __restrict__ outrow,
                                                  float* __restrict__ partials,
                                                  int n, int do_relu) {
    __shared__ int   sm_s[4][64];
    __shared__ float sm_w[4][64];
    __shared__ float red[256];
    int tid = threadIdx.x;
    int lane = tid & 63, wid = tid >> 6;
    int half = lane >> 5, fp = lane & 31;      // feature-pair index
    const char* h2b = (const char*)h2;
    unsigned fpo = (unsigned)fp << 2;          // byte offset of ushort2 in row
    float b0 = bias[2 * fp], b1 = bias[2 * fp + 1];
    float msum0 = 0.f, msum1 = 0.f;

    int gwave = (blockIdx.x * blockDim.x + tid) >> 6;
    int nwaves = (gridDim.x * blockDim.x) >> 6;
    for (int node = gwave; node < n; node += nwaves) {
        int beg = ptr[node], end = ptr[node + 1];
        float ad = adst[node];
        float acc0 = 0.f, acc1 = 0.f, wsum = 0.f;
        for (int b = beg; b < end; b += 64) {
            int blen = end - b; if (blen > 64) blen = 64;
            int sv = 0; float wv = 0.f;
            if (lane < blen) {
                sv = srcs[b + lane];             // coalesced
                float e = asrc[sv] + ad;         // L2-resident 4B gather
                e = (e > 0.f) ? e : NEG_SLOPE * e;
                wv = __expf(e);
            }
            wsum += wv;
            sm_s[wid][lane] = sv;
            sm_w[wid][lane] = wv;
            int npf = blen >> 1;                 // full edge-pairs
            int j = 0;
            for (; j + 8 <= npf; j += 8) {
                int ss[8]; float ww[8]; unsigned gg[8];
#pragma unroll
                for (int u = 0; u < 8; ++u) {
                    int e0 = 2 * (j + u) + half;
                    ss[u] = sm_s[wid][e0];
                    ww[u] = sm_w[wid][e0];
                }
#pragma unroll
                for (int u = 0; u < 8; ++u)
                    gg[u] = *(const unsigned*)(h2b + (((unsigned)ss[u] << 7) + fpo));
#pragma unroll
                for (int u = 0; u < 8; ++u) {
                    acc0 = fmaf(ww[u], bflo(gg[u]), acc0);
                    acc1 = fmaf(ww[u], bfhi(gg[u]), acc1);
                }
            }
            for (; j < npf; ++j) {
                int e0 = 2 * j + half;
                int s0 = sm_s[wid][e0];
                float w0 = sm_w[wid][e0];
                unsigned g0 = *(const unsigned*)(h2b + (((unsigned)s0 << 7) + fpo));
                acc0 = fmaf(w0, bflo(g0), acc0);
                acc1 = fmaf(w0, bfhi(g0), acc1);
            }
            if (blen & 1) {                      // last odd edge: half0 only
                int e0 = blen - 1;
                int s0 = sm_s[wid][e0];
                float w0 = (half == 0) ? sm_w[wid][e0] : 0.f;
                unsigned g0 = *(const unsigned*)(h2b + (((unsigned)s0 << 7) + fpo));
                acc0 = fmaf(w0, bflo(g0), acc0);
                acc1 = fmaf(w0, bfhi(g0), acc1);
            }
        }
        acc0 += __shfl_xor(acc0, 32);            // combine even/odd halves
        acc1 += __shfl_xor(acc1, 32);
#pragma unroll
        for (int off = 32; off; off >>= 1) wsum += __shfl_xor(wsum, off);
        float inv = 1.f / (wsum + 1e-16f);
        float o0 = acc0 * inv + b0;
        float o1 = acc1 * inv + b1;
        if (!FMEAN) {
            if (do_relu) { o0 = fmaxf(o0, 0.f); o1 = fmaxf(o1, 0.f); }
            if (half == 0)
                *(float2*)(outrow + (size_t)node * 64 + 2 * fp) = make_float2(o0, o1);
        } else {
            if (half == 0) { msum0 += o0; msum1 += o1; }
        }
    }
    if (FMEAN) {
        if (half == 0) {
            red[wid * 64 + 2 * fp] = msum0;
            red[wid * 64 + 2 * fp + 1] = msum1;
        } else {
            red[wid * 64 + 2 * fp] = 0.f;       // overwritten by half0 below
        }
        __syncthreads();
        if (tid < 64) {
            float t = red[tid] + red[64 + tid] + red[128 + tid] + red[192 + tid];
            partials[(size_t)blockIdx.x * 64 + tid] = t;
        }
    }
}

// Final mean: sum partial rows, scale, atomic into out.
__global__ __launch_bounds__(256) void reduce_mean(const float* __restrict__ partials,
                                                   float* __restrict__ out,
                                                   int nb, float inv_n) {
    __shared__ float red[256];
    int f = threadIdx.x & 63;
    int w = threadIdx.x >> 6;
    int idx = blockIdx.x * 4 + w;
    int stride = gridDim.x * 4;
    float s = 0.f;
    for (int r = idx; r < nb; r += stride) s += partials[(size_t)r * 64 + f];
    red[threadIdx.x] = s;
    __syncthreads();
    if (w == 0) {
        float t = red[f] + red[64 + f] + red[128 + f] + red[192 + f];
        atomicAdd(&out[f], t * inv_n);
    }
}

extern "C" void kernel_launch(void* const* d_in, const int* in_sizes, int n_in,
                              void* d_out, int out_size, void* d_ws, size_t ws_size,
                              hipStream_t stream) {
    const float* x   = (const float*)d_in[0];
    const int*   ei  = (const int*)d_in[1];
    // d_in[2] = edge_attr (unused by reference, edge_dim=None)
    const float* W1  = (const float*)d_in[3];
    const float* as1 = (const float*)d_in[4];
    const float* ad1 = (const float*)d_in[5];
    const float* b1  = (const float*)d_in[6];
    const float* W2  = (const float*)d_in[7];
    const float* as2 = (const float*)d_in[8];
    const float* ad2 = (const float*)d_in[9];
    const float* b2  = (const float*)d_in[10];
    float* out = (float*)d_out;

    const int N = in_sizes[0] / 128;  // 100000
    const int E = in_sizes[1] / 2;    // 1600000
    const int T = E + N;              // edges incl. self-loops

    const int NBUK = (N + (1 << BUCKET_SHIFT) - 1) >> BUCKET_SHIFT;   // 196
    const int NBLK = (T + CHUNK - 1) / CHUNK;                          // 208
    const int NHH  = NBUK * NBLK;
    const int NBS  = (NHH + SCAN_ELEMS - 1) / SCAN_ELEMS;
    const int AGRID = (N + 3) / 4;    // one node per wave

    // Workspace carve-up (256B-aligned)
    size_t off = 0;
    char* base = (char*)d_ws;
    auto alloc = [&](size_t bytes) -> void* {
        void* p = base + off;
        off += (bytes + 255) & ~(size_t)255;
        return p;
    };
    int*   flag    = (int*)alloc(4);
    int*   ptr     = (int*)alloc(((size_t)N + 1) * 4);
    int*   bsums   = (int*)alloc(256 * 4);
    int*   HH      = (int*)alloc((size_t)NHH * 4);
    int*   scanHH  = (int*)alloc((size_t)NHH * 4);
    int*   csr_src = (int*)alloc((size_t)T * 4);
    float* asrc    = (float*)alloc((size_t)N * 4);
    float* adst    = (float*)alloc((size_t)N * 4);
    unsigned short* h2 = (unsigned short*)alloc((size_t)N * 64 * 2);
    float* bufB    = (float*)alloc((size_t)N * 64 * 4);
    int*   sorted  = (int*)bufB;      // overlay: dead before agg1 writes bufB
    float* partials = bufB;           // overlay: bufB dead after proj2 reads it
    (void)ws_size;

    // --- CSR build via counting sort (shared by both layers) ---
    detect_kernel<<<1, 256, 0, stream>>>(ei, flag);
    p1_hist<<<NBLK, 256, 0, stream>>>(ei, flag, HH, E, N, NBLK);
    scan1_kernel<<<NBS, 256, 0, stream>>>(HH, bsums, NHH);
    scan2_kernel<<<1, 256, 0, stream>>>(bsums, NBS);
    scan3g_kernel<<<NBS, 256, 0, stream>>>(HH, bsums, scanHH, NHH);
    p3_scatter<<<NBLK, 256, 0, stream>>>(ei, flag, scanHH, sorted, E, N, NBLK);
    p4_finalize<<<NBUK, 256, 0, stream>>>(scanHH, sorted, ptr, csr_src, N, NBLK, T);

    const int PGRID = (N + 63) / 64;

    // --- Layer 1: proj (x @ W1) -> bf16 h2 + attention aggregate + ReLU ---
    proj_gemm<128><<<PGRID, 256, 0, stream>>>(x, W1, as1, ad1, h2, asrc, adst, N);
    agg_kernel<false><<<AGRID, 256, 0, stream>>>(ptr, csr_src, h2, asrc, adst,
                                                 b1, bufB, nullptr, N, 1);

    // --- Layer 2: proj (h @ W2) -> bf16 h2 + attention aggregate + mean ---
    proj_gemm<64><<<PGRID, 256, 0, stream>>>(bufB, W2, as2, ad2, h2, asrc, adst, N);
    agg_kernel<true><<<AGRID, 256, 0, stream>>>(ptr, csr_src, h2, asrc, adst,
                                                b2, nullptr, partials, N, 0);
    hipMemsetAsync(out, 0, 64 * 4, stream);
    reduce_mean<<<64, 256, 0, stream>>>(partials, out, AGRID, 1.f / (float)N);
}

// Round 9
// 375.935 us; speedup vs baseline: 1.0885x; 1.0885x over previous
//
#include <hip/hip_runtime.h>
#include <hip/hip_bf16.h>
#include <cstdint>

#define NEG_SLOPE 0.2f
#define SCAN_ELEMS 1024   // elements per scan block (256 thr x 4)
#define BUCKET_SHIFT 9    // 512 nodes per bucket
#define CHUNK 8192        // edges per bucketing block

__device__ inline unsigned short f2bf(float f) {  // round-to-nearest-even
    unsigned xi = __float_as_uint(f);
    unsigned r = xi + 0x7fffu + ((xi >> 16) & 1u);
    return (unsigned short)(r >> 16);
}
__device__ inline float bflo(unsigned g) { return __uint_as_float((g & 0xffffu) << 16); }
__device__ inline float bfhi(unsigned g) { return __uint_as_float(g & 0xffff0000u); }

__device__ inline int get_ei(const int* ei, int is64, long idx) {
    return is64 ? ei[2 * idx] : ei[(int)idx];
}

// In-block int64 detection: OR of odd words of the first 2048 src entries
// (zero for little-endian int64 ids < 2^31; random node ids for int32).
// Computed redundantly per block -- 8 KB L2-hot read, no extra dispatch.
__device__ inline int detect_is64(const int* __restrict__ ei, int tid) {
    __shared__ int dred[4];
    int v = 0;
    for (int i = tid; i < 2048; i += 256) v |= ei[2 * i + 1];
#pragma unroll
    for (int off = 32; off; off >>= 1) v |= __shfl_xor(v, off);
    if ((tid & 63) == 0) dred[tid >> 6] = v;
    __syncthreads();
    int r = dred[0] | dred[1] | dred[2] | dred[3];
    __syncthreads();   // protect dred reuse safety across callers
    return (r == 0) ? 1 : 0;
}

// ---------------------------------------------------------------------------
// Counting-sort CSR build.
// p1: per-(block,chunk) LDS histogram over dst-buckets -> HH[bucket][blk]
// ---------------------------------------------------------------------------
__global__ __launch_bounds__(256) void p1_hist(const int* __restrict__ ei,
                                               int* __restrict__ HH,
                                               int E, int n, int nblk) {
    __shared__ int cnt[256];
    int tid = threadIdx.x;
    int is64 = detect_is64(ei, tid);
    int nbuk = (n + (1 << BUCKET_SHIFT) - 1) >> BUCKET_SHIFT;  // <=256
    for (int b = tid; b < nbuk; b += 256) cnt[b] = 0;
    __syncthreads();
    int total = E + n;
    int beg = blockIdx.x * CHUNK;
    int end = beg + CHUNK; if (end > total) end = total;
    for (int i = beg + tid; i < end; i += 256) {
        int d = (i < E) ? get_ei(ei, is64, (long)E + i) : (i - E);
        atomicAdd(&cnt[d >> BUCKET_SHIFT], 1);
    }
    __syncthreads();
    for (int b = tid; b < nbuk; b += 256) HH[b * nblk + blockIdx.x] = cnt[b];
}

// scan phase 1: per-block sums of an int array
__global__ __launch_bounds__(256) void scan1_kernel(const int* __restrict__ src,
                                                    int* __restrict__ bsums, int n) {
    int t = threadIdx.x;
    int i0 = blockIdx.x * SCAN_ELEMS + 4 * t;
    int4 v = make_int4(0, 0, 0, 0);
    if (i0 + 3 < n) v = *(const int4*)(src + i0);
    else {
        if (i0 + 0 < n) v.x = src[i0 + 0];
        if (i0 + 1 < n) v.y = src[i0 + 1];
        if (i0 + 2 < n) v.z = src[i0 + 2];
        if (i0 + 3 < n) v.w = src[i0 + 3];
    }
    int s = v.x + v.y + v.z + v.w;
#pragma unroll
    for (int off = 32; off; off >>= 1) s += __shfl_down(s, off);
    __shared__ int ws[4];
    if ((t & 63) == 0) ws[t >> 6] = s;
    __syncthreads();
    if (t == 0) bsums[blockIdx.x] = ws[0] + ws[1] + ws[2] + ws[3];
}

// scan phase 2+3 fused: each block locally scans the (<=256) block sums,
// then produces its exclusive-scan output chunk.
__global__ __launch_bounds__(256) void scan3g_kernel(const int* __restrict__ src,
                                                     const int* __restrict__ bsums,
                                                     int* __restrict__ out, int n, int nb) {
    int b = blockIdx.x;
    int t = threadIdx.x;
    // local exclusive scan of bsums
    __shared__ int sb[256];
    int bv = (t < nb) ? bsums[t] : 0;
    sb[t] = bv;
    __syncthreads();
    for (int off = 1; off < 256; off <<= 1) {
        int u = (t >= off) ? sb[t - off] : 0;
        __syncthreads();
        sb[t] += u;
        __syncthreads();
    }
    int blockbase = (b == 0) ? 0 : sb[b - 1];

    int i0 = b * SCAN_ELEMS + 4 * t;
    int4 v = make_int4(0, 0, 0, 0);
    if (i0 + 3 < n) v = *(const int4*)(src + i0);
    else {
        if (i0 + 0 < n) v.x = src[i0 + 0];
        if (i0 + 1 < n) v.y = src[i0 + 1];
        if (i0 + 2 < n) v.z = src[i0 + 2];
        if (i0 + 3 < n) v.w = src[i0 + 3];
    }
    int s0 = v.x, s1 = s0 + v.y, s2 = s1 + v.z, s3 = s2 + v.w;
    __shared__ int sh[256];
    sh[t] = s3;
    __syncthreads();
    for (int off = 1; off < 256; off <<= 1) {
        int u = (t >= off) ? sh[t - off] : 0;
        __syncthreads();
        sh[t] += u;
        __syncthreads();
    }
    int base = blockbase + sh[t] - s3;
    if (i0 + 0 < n) out[i0 + 0] = base;
    if (i0 + 1 < n) out[i0 + 1] = base + s0;
    if (i0 + 2 < n) out[i0 + 2] = base + s1;
    if (i0 + 3 < n) out[i0 + 3] = base + s2;
}

// p3: scatter edges into bucket-sorted PACKED array (s<<9 | d&511).
__global__ __launch_bounds__(256) void p3_scatter(const int* __restrict__ ei,
                                                  const int* __restrict__ scanHH,
                                                  int* __restrict__ sorted,
                                                  int E, int n, int nblk) {
    __shared__ int base[256];
    __shared__ int cur[256];
    int tid = threadIdx.x;
    int is64 = detect_is64(ei, tid);
    int nbuk = (n + (1 << BUCKET_SHIFT) - 1) >> BUCKET_SHIFT;
    for (int b = tid; b < nbuk; b += 256) {
        base[b] = scanHH[b * nblk + blockIdx.x];
        cur[b] = 0;
    }
    __syncthreads();
    int total = E + n;
    int beg = blockIdx.x * CHUNK;
    int end = beg + CHUNK; if (end > total) end = total;
    for (int i = beg + tid; i < end; i += 256) {
        int s, d;
        if (i < E) {
            s = get_ei(ei, is64, i);
            d = get_ei(ei, is64, (long)E + i);
        } else {
            s = d = i - E;
        }
        int b = d >> BUCKET_SHIFT;
        int p = base[b] + atomicAdd(&cur[b], 1);
        sorted[p] = (s << BUCKET_SHIFT) | (d & ((1 << BUCKET_SHIFT) - 1));
    }
}

// p4: one block per bucket -> ptr + csr_src.
__global__ __launch_bounds__(256) void p4_finalize(const int* __restrict__ scanHH,
                                                   const int* __restrict__ sorted,
                                                   int* __restrict__ ptr,
                                                   int* __restrict__ csr_src,
                                                   int n, int nblk, int T) {
    int b = blockIdx.x;
    int nbuk = gridDim.x;
    int tid = threadIdx.x;
    int node0 = b << BUCKET_SHIFT;
    int nn = n - node0; if (nn > (1 << BUCKET_SHIFT)) nn = 1 << BUCKET_SHIFT;
    int beg = scanHH[b * nblk];
    int end = (b + 1 < nbuk) ? scanHH[(b + 1) * nblk] : T;

    __shared__ int cnt[512];
    __shared__ int pair[256];
    __shared__ int exc[512];
    cnt[tid] = 0; cnt[tid + 256] = 0;
    __syncthreads();
    for (int j = beg + tid; j < end; j += 256) {
        int v = sorted[j];
        atomicAdd(&cnt[v & ((1 << BUCKET_SHIFT) - 1)], 1);
    }
    __syncthreads();
    int psum = cnt[2 * tid] + cnt[2 * tid + 1];
    pair[tid] = psum;
    __syncthreads();
    for (int off = 1; off < 256; off <<= 1) {
        int u = (tid >= off) ? pair[tid - off] : 0;
        __syncthreads();
        pair[tid] += u;
        __syncthreads();
    }
    int pexc = pair[tid] - psum;
    exc[2 * tid] = pexc;
    exc[2 * tid + 1] = pexc + cnt[2 * tid];
    __syncthreads();
    for (int i = tid; i < nn; i += 256) ptr[node0 + i] = beg + exc[i];
    if (node0 + nn == n && tid == 0) ptr[n] = T;
    cnt[tid] = exc[tid]; cnt[tid + 256] = exc[tid + 256];
    __syncthreads();
    for (int j = beg + tid; j < end; j += 256) {
        int v = sorted[j];
        int p = beg + atomicAdd(&cnt[v & ((1 << BUCKET_SHIFT) - 1)], 1);
        csr_src[p] = ((unsigned)v) >> BUCKET_SHIFT;
    }
}

// ---------------------------------------------------------------------------
// Projection as register-tiled GEMM; emits bf16 h2 + fp32 asrc/adst.
// ---------------------------------------------------------------------------
template <int K>
__global__ __launch_bounds__(256) void proj_gemm(const float* __restrict__ x,
                                                 const float* __restrict__ W,
                                                 const float* __restrict__ att_s,
                                                 const float* __restrict__ att_d,
                                                 unsigned short* __restrict__ h2,
                                                 float* __restrict__ asrc,
                                                 float* __restrict__ adst, int n) {
    constexpr int KP = K + 4;
    constexpr int ROWF4 = K / 4;
    __shared__ float xs[64 * KP];
    int tid = threadIdx.x;
    int node0 = blockIdx.x * 64;

#pragma unroll
    for (int r = 0; r < (64 * ROWF4) / 256; ++r) {
        int f4 = tid + 256 * r;
        int row = f4 / ROWF4, c4 = f4 % ROWF4;
        float4 v = make_float4(0.f, 0.f, 0.f, 0.f);
        if (node0 + row < n) v = *(const float4*)(x + (size_t)(node0 + row) * K + 4 * c4);
        *(float4*)(xs + row * KP + 4 * c4) = v;
    }
    __syncthreads();

    int tf = tid & 15, tn = tid >> 4;
    float acc[4][4];
#pragma unroll
    for (int i = 0; i < 4; ++i)
#pragma unroll
        for (int j = 0; j < 4; ++j) acc[i][j] = 0.f;

    const float* wp = W + 4 * tf;
    const float* xp = xs + 4 * tn * KP;
#pragma unroll 4
    for (int k4 = 0; k4 < K / 4; ++k4) {
        float4 wv[4];
#pragma unroll
        for (int kk = 0; kk < 4; ++kk)
            wv[kk] = *(const float4*)(wp + (size_t)(4 * k4 + kk) * 64);
        float4 xv[4];
#pragma unroll
        for (int i = 0; i < 4; ++i)
            xv[i] = *(const float4*)(xp + i * KP + 4 * k4);
#pragma unroll
        for (int i = 0; i < 4; ++i) {
            const float xk[4] = {xv[i].x, xv[i].y, xv[i].z, xv[i].w};
#pragma unroll
            for (int kk = 0; kk < 4; ++kk) {
                const float* wf = (const float*)&wv[kk];
#pragma unroll
                for (int j = 0; j < 4; ++j) acc[i][j] = fmaf(xk[kk], wf[j], acc[i][j]);
            }
        }
    }

    float4 as = *(const float4*)(att_s + 4 * tf);
    float4 ad = *(const float4*)(att_d + 4 * tf);
#pragma unroll
    for (int i = 0; i < 4; ++i) {
        int node = node0 + 4 * tn + i;
        float ps = acc[i][0] * as.x + acc[i][1] * as.y + acc[i][2] * as.z + acc[i][3] * as.w;
        float pd = acc[i][0] * ad.x + acc[i][1] * ad.y + acc[i][2] * ad.z + acc[i][3] * ad.w;
#pragma unroll
        for (int off = 1; off < 16; off <<= 1) {
            ps += __shfl_xor(ps, off);
            pd += __shfl_xor(pd, off);
        }
        if (node < n) {
            ushort4 u;
            u.x = f2bf(acc[i][0]); u.y = f2bf(acc[i][1]);
            u.z = f2bf(acc[i][2]); u.w = f2bf(acc[i][3]);
            *(ushort4*)(h2 + (size_t)node * 64 + 4 * tf) = u;
            if (tf == 0) { asrc[node] = ps; adst[node] = pd; }
        }
    }
}

// ---------------------------------------------------------------------------
// Fused edge softmax + aggregation, half-wave ushort2 scheme.
// Zero-remainder: all 64 sm slots are zero-filled (wv=0, sv=0 for OOB lanes),
// so the pair loop rounds UP to whole x4 blocks -- wasted slots do
// fma(0, h2-row-0) against one L1-hot line. No scalar remainder, no odd case.
// ---------------------------------------------------------------------------
template <bool FMEAN>
__global__ __launch_bounds__(256) void agg_kernel(const int* __restrict__ ptr,
                                                  const int* __restrict__ srcs,
                                                  const unsigned short* __restrict__ h2,
                                                  const float* __restrict__ asrc,
                                                  const float* __restrict__ adst,
                                                  const float* __restrict__ bias,
                                                  float* __restrict__ outrow,
                                                  float* __restrict__ partials,
                                                  int n, int do_relu) {
    __shared__ int   sm_s[4][64];
    __shared__ float sm_w[4][64];
    __shared__ float red[256];
    int tid = threadIdx.x;
    int lane = tid & 63, wid = tid >> 6;
    int half = lane >> 5, fp = lane & 31;      // feature-pair index
    const char* h2b = (const char*)h2;
    unsigned fpo = (unsigned)fp << 2;          // byte offset of ushort2 in row
    float b0 = bias[2 * fp], b1 = bias[2 * fp + 1];
    float msum0 = 0.f, msum1 = 0.f;

    int gwave = (blockIdx.x * blockDim.x + tid) >> 6;
    int nwaves = (gridDim.x * blockDim.x) >> 6;
    for (int node = gwave; node < n; node += nwaves) {
        int beg = ptr[node], end = ptr[node + 1];
        float ad = adst[node];
        float acc0 = 0.f, acc1 = 0.f, wsum = 0.f;
        for (int b = beg; b < end; b += 64) {
            int blen = end - b; if (blen > 64) blen = 64;
            int sv = 0; float wv = 0.f;
            if (lane < blen) {
                sv = srcs[b + lane];             // coalesced
                float e = asrc[sv] + ad;         // L2-resident 4B gather
                e = (e > 0.f) ? e : NEG_SLOPE * e;
                wv = __expf(e);
            }
            wsum += wv;
            sm_s[wid][lane] = sv;
            sm_w[wid][lane] = wv;
            int np4 = ((((blen + 1) >> 1) + 3) >> 2);   // whole x4 pair-blocks
            for (int j4 = 0; j4 < np4; ++j4) {
                int jb = 4 * j4;
                int ss[4]; float ww[4]; unsigned gg[4];
#pragma unroll
                for (int u = 0; u < 4; ++u) {
                    int e0 = 2 * (jb + u) + half;
                    ss[u] = sm_s[wid][e0];
                    ww[u] = sm_w[wid][e0];
                }
#pragma unroll
                for (int u = 0; u < 4; ++u)
                    gg[u] = *(const unsigned*)(h2b + (((unsigned)ss[u] << 7) + fpo));
#pragma unroll
                for (int u = 0; u < 4; ++u) {
                    acc0 = fmaf(ww[u], bflo(gg[u]), acc0);
                    acc1 = fmaf(ww[u], bfhi(gg[u]), acc1);
                }
            }
        }
        acc0 += __shfl_xor(acc0, 32);            // combine even/odd halves
        acc1 += __shfl_xor(acc1, 32);
#pragma unroll
        for (int off = 32; off; off >>= 1) wsum += __shfl_xor(wsum, off);
        float inv = 1.f / (wsum + 1e-16f);
        float o0 = acc0 * inv + b0;
        float o1 = acc1 * inv + b1;
        if (!FMEAN) {
            if (do_relu) { o0 = fmaxf(o0, 0.f); o1 = fmaxf(o1, 0.f); }
            if (half == 0)
                *(float2*)(outrow + (size_t)node * 64 + 2 * fp) = make_float2(o0, o1);
        } else {
            if (half == 0) { msum0 += o0; msum1 += o1; }
        }
    }
    if (FMEAN) {
        // half0 lanes (fp=0..31) cover all 64 slots of this wave's row.
        if (half == 0) {
            red[wid * 64 + 2 * fp] = msum0;
            red[wid * 64 + 2 * fp + 1] = msum1;
        }
        __syncthreads();
        if (tid < 64) {
            float t = red[tid] + red[64 + tid] + red[128 + tid] + red[192 + tid];
            partials[(size_t)blockIdx.x * 64 + tid] = t;
        }
    }
}

// Final mean: sum partial rows, scale, atomic into out.
__global__ __launch_bounds__(256) void reduce_mean(const float* __restrict__ partials,
                                                   float* __restrict__ out,
                                                   int nb, float inv_n) {
    __shared__ float red[256];
    int f = threadIdx.x & 63;
    int w = threadIdx.x >> 6;
    int idx = blockIdx.x * 4 + w;
    int stride = gridDim.x * 4;
    float s = 0.f;
    for (int r = idx; r < nb; r += stride) s += partials[(size_t)r * 64 + f];
    red[threadIdx.x] = s;
    __syncthreads();
    if (w == 0) {
        float t = red[f] + red[64 + f] + red[128 + f] + red[192 + f];
        atomicAdd(&out[f], t * inv_n);
    }
}

extern "C" void kernel_launch(void* const* d_in, const int* in_sizes, int n_in,
                              void* d_out, int out_size, void* d_ws, size_t ws_size,
                              hipStream_t stream) {
    const float* x   = (const float*)d_in[0];
    const int*   ei  = (const int*)d_in[1];
    // d_in[2] = edge_attr (unused by reference, edge_dim=None)
    const float* W1  = (const float*)d_in[3];
    const float* as1 = (const float*)d_in[4];
    const float* ad1 = (const float*)d_in[5];
    const float* b1  = (const float*)d_in[6];
    const float* W2  = (const float*)d_in[7];
    const float* as2 = (const float*)d_in[8];
    const float* ad2 = (const float*)d_in[9];
    const float* b2  = (const float*)d_in[10];
    float* out = (float*)d_out;

    const int N = in_sizes[0] / 128;  // 100000
    const int E = in_sizes[1] / 2;    // 1600000
    const int T = E + N;              // edges incl. self-loops

    const int NBUK = (N + (1 << BUCKET_SHIFT) - 1) >> BUCKET_SHIFT;   // 196
    const int NBLK = (T + CHUNK - 1) / CHUNK;                          // 208
    const int NHH  = NBUK * NBLK;
    const int NBS  = (NHH + SCAN_ELEMS - 1) / SCAN_ELEMS;              // 40
    const int AGRID = (N + 3) / 4;    // one node per wave

    // Workspace carve-up (256B-aligned)
    size_t off = 0;
    char* base = (char*)d_ws;
    auto alloc = [&](size_t bytes) -> void* {
        void* p = base + off;
        off += (bytes + 255) & ~(size_t)255;
        return p;
    };
    int*   ptr     = (int*)alloc(((size_t)N + 1) * 4);
    int*   bsums   = (int*)alloc(256 * 4);
    int*   HH      = (int*)alloc((size_t)NHH * 4);
    int*   scanHH  = (int*)alloc((size_t)NHH * 4);
    int*   csr_src = (int*)alloc((size_t)T * 4);
    float* asrc    = (float*)alloc((size_t)N * 4);
    float* adst    = (float*)alloc((size_t)N * 4);
    unsigned short* h2 = (unsigned short*)alloc((size_t)N * 64 * 2);
    float* bufB    = (float*)alloc((size_t)N * 64 * 4);
    int*   sorted  = (int*)bufB;      // overlay: dead before agg1 writes bufB
    float* partials = bufB;           // overlay: bufB dead after proj2 reads it
    (void)ws_size;

    // --- CSR build via counting sort (shared by both layers) ---
    p1_hist<<<NBLK, 256, 0, stream>>>(ei, HH, E, N, NBLK);
    scan1_kernel<<<NBS, 256, 0, stream>>>(HH, bsums, NHH);
    scan3g_kernel<<<NBS, 256, 0, stream>>>(HH, bsums, scanHH, NHH, NBS);
    p3_scatter<<<NBLK, 256, 0, stream>>>(ei, scanHH, sorted, E, N, NBLK);
    p4_finalize<<<NBUK, 256, 0, stream>>>(scanHH, sorted, ptr, csr_src, N, NBLK, T);

    const int PGRID = (N + 63) / 64;

    // --- Layer 1: proj (x @ W1) -> bf16 h2 + attention aggregate + ReLU ---
    proj_gemm<128><<<PGRID, 256, 0, stream>>>(x, W1, as1, ad1, h2, asrc, adst, N);
    agg_kernel<false><<<AGRID, 256, 0, stream>>>(ptr, csr_src, h2, asrc, adst,
                                                 b1, bufB, nullptr, N, 1);

    // --- Layer 2: proj (h @ W2) -> bf16 h2 + attention aggregate + mean ---
    proj_gemm<64><<<PGRID, 256, 0, stream>>>(bufB, W2, as2, ad2, h2, asrc, adst, N);
    agg_kernel<true><<<AGRID, 256, 0, stream>>>(ptr, csr_src, h2, asrc, adst,
                                                b2, nullptr, partials, N, 0);
    hipMemsetAsync(out, 0, 64 * 4, stream);
    reduce_mean<<<64, 256, 0, stream>>>(partials, out, AGRID, 1.f / (float)N);
}